// Round 3
// baseline (185.652 us; speedup 1.0000x reference)
//
#include <hip/hip_runtime.h>
#include <stdint.h>

#define B_DET 8192
#define N_DIM 256
#define T_TRK 4096
#define Q_SLOT 64
#define MAXD   32          // max detections/track staged; Poisson(2) max over 4096 tracks ~11
#define EPSF   1e-9f

// Monotone map fp32 -> uint32 (ascending). No NaNs expected in this data.
__device__ __forceinline__ uint32_t f32_key(float f) {
    uint32_t u = __float_as_uint(f);
    return (u & 0x80000000u) ? ~u : (u | 0x80000000u);
}

// Pass 1: bucket detections by track. cnt[] must be zeroed beforehand.
__global__ __launch_bounds__(256)
void build_lists(const int* __restrict__ track_idxs,
                 int* __restrict__ cnt, int* __restrict__ list) {
    const int b = blockIdx.x * 256 + threadIdx.x;
    const int t = track_idxs[b];
    const int slot = atomicAdd(&cnt[t], 1);
    if (slot < MAXD) list[t * MAXD + slot] = b;
}

// Pass 2: one block per track. Stage the track's detection reprs in LDS;
// each wave handles 16 slots: read memory row once, argmin over detections
// (packed (f32key(dot), b) min == exact first-occurrence tie-break), blend,
// renormalize, write out. cnt==0 tracks are a pure passthrough copy.
__global__ __launch_bounds__(256)
void fused_update(const float* __restrict__ reprs,
                  const float* __restrict__ memory,
                  const float* __restrict__ alpha,
                  const int* __restrict__ cnt,
                  const int* __restrict__ list,
                  float* __restrict__ out) {
    const int t    = blockIdx.x;
    const int wave = threadIdx.x >> 6;
    const int lane = threadIdx.x & 63;
    const size_t tbase = (size_t)t * Q_SLOT * N_DIM;

    int D = cnt[t];
    if (D == 0) {
        // untouched track: copy 64 rows (64 KB) straight through
        #pragma unroll 4
        for (int s = 0; s < 16; ++s) {
            const size_t off = tbase + (size_t)(wave * 16 + s) * N_DIM;
            const float4 m = reinterpret_cast<const float4*>(memory + off)[lane];
            reinterpret_cast<float4*>(out + off)[lane] = m;
        }
        return;
    }
    if (D > MAXD) D = MAXD;

    __shared__ float rsh[MAXD][N_DIM];
    __shared__ int   bsh[MAXD];

    for (int d = 0; d < D; ++d) {
        const int b = list[t * MAXD + d];          // uniform across block
        if (threadIdx.x == 0) bsh[d] = b;
        rsh[d][threadIdx.x] = reprs[(size_t)b * N_DIM + threadIdx.x];
    }
    __syncthreads();

    for (int s = 0; s < 16; ++s) {
        const int q = wave * 16 + s;
        const size_t off = tbase + (size_t)q * N_DIM;
        const float4 m = reinterpret_cast<const float4*>(memory + off)[lane];

        unsigned long long best = ~0ULL;
        for (int d = 0; d < D; ++d) {
            const float4 r = reinterpret_cast<const float4*>(&rsh[d][0])[lane];
            float dot = m.x * r.x + m.y * r.y + m.z * r.z + m.w * r.w;
            #pragma unroll
            for (int o = 32; o >= 1; o >>= 1)
                dot += __shfl_xor(dot, o, 64);
            const unsigned long long p =
                ((unsigned long long)f32_key(dot) << 32) | (uint32_t)bsh[d];
            best = (p < best) ? p : best;
        }

        const int bsel = (int)(uint32_t)best;
        int dsel = 0;
        for (int d = 0; d < D; ++d) { if (bsh[d] == bsel) { dsel = d; break; } }

        const float a  = alpha[q];
        const float na = 1.0f - a;
        const float4 r = reinterpret_cast<const float4*>(&rsh[dsel][0])[lane];

        float4 u;
        u.x = a * m.x + na * r.x;
        u.y = a * m.y + na * r.y;
        u.z = a * m.z + na * r.z;
        u.w = a * m.w + na * r.w;

        float ss = u.x * u.x + u.y * u.y + u.z * u.z + u.w * u.w;
        #pragma unroll
        for (int o = 32; o >= 1; o >>= 1)
            ss += __shfl_xor(ss, o, 64);

        const float sc = 1.0f / (sqrtf(ss) + EPSF);
        u.x *= sc; u.y *= sc; u.z *= sc; u.w *= sc;
        reinterpret_cast<float4*>(out + off)[lane] = u;
    }
}

extern "C" void kernel_launch(void* const* d_in, const int* in_sizes, int n_in,
                              void* d_out, int out_size, void* d_ws, size_t ws_size,
                              hipStream_t stream) {
    const float* reprs      = (const float*)d_in[0];
    const float* memory     = (const float*)d_in[1];
    const float* alpha      = (const float*)d_in[2];
    const int*   track_idxs = (const int*)d_in[3];   // harness converts int64 -> int32
    float*       out        = (float*)d_out;

    int* cnt  = (int*)d_ws;                               // 16 KB
    int* list = (int*)((char*)d_ws + T_TRK * sizeof(int)); // 512 KB

    hipMemsetAsync(cnt, 0, T_TRK * sizeof(int), stream);
    build_lists<<<B_DET / 256, 256, 0, stream>>>(track_idxs, cnt, list);
    fused_update<<<T_TRK, 256, 0, stream>>>(reprs, memory, alpha, cnt, list, out);
}

// Round 4
// 146.077 us; speedup vs baseline: 1.2709x; 1.2709x over previous
//
#include <hip/hip_runtime.h>
#include <stdint.h>

#define B_DET 8192
#define N_DIM 256
#define T_TRK 4096
#define Q_SLOT 64
#define MAXD   32          // max detections/track staged; observed max (fixed seed) well below
#define EPSF   1e-9f

// Monotone map fp32 -> uint32 (ascending). No NaNs expected in this data.
__device__ __forceinline__ uint32_t f32_key(float f) {
    uint32_t u = __float_as_uint(f);
    return (u & 0x80000000u) ? ~u : (u | 0x80000000u);
}

// Pass 1: bucket detections by track. cnt[] must be zeroed beforehand.
__global__ __launch_bounds__(256)
void build_lists(const int* __restrict__ track_idxs,
                 int* __restrict__ cnt, int* __restrict__ list) {
    const int b = blockIdx.x * 256 + threadIdx.x;
    const int t = track_idxs[b];
    const int slot = atomicAdd(&cnt[t], 1);
    if (slot < MAXD) list[t * MAXD + slot] = b;
}

// Pass 2: one block per track, 4 waves x 16 slots. Preload all 16 memory rows
// per wave into registers (MLP), argmin over detections with packed
// (f32key(dot), b, d) u64 min (exact first-occurrence tie-break), blend, and
// renormalize via closed form ||a*m+(1-a)*r||^2 = a^2 + (1-a)^2*||r||^2 +
// 2*a*(1-a)*dot  (memory rows are unit-norm by construction).
__global__ __launch_bounds__(256)
void fused_update(const float* __restrict__ reprs,
                  const float* __restrict__ memory,
                  const float* __restrict__ alpha,
                  const int* __restrict__ cnt,
                  const int* __restrict__ list,
                  float* __restrict__ out) {
    const int t    = blockIdx.x;
    const int wave = threadIdx.x >> 6;
    const int lane = threadIdx.x & 63;
    const size_t wbase = ((size_t)t * Q_SLOT + wave * 16) * N_DIM;

    int D = cnt[t];
    if (D == 0) {
        // untouched track: batched 16-row register copy (16 loads in flight)
        float4 m[16];
        #pragma unroll
        for (int s = 0; s < 16; ++s)
            m[s] = reinterpret_cast<const float4*>(memory + wbase + (size_t)s * N_DIM)[lane];
        #pragma unroll
        for (int s = 0; s < 16; ++s)
            reinterpret_cast<float4*>(out + wbase + (size_t)s * N_DIM)[lane] = m[s];
        return;
    }
    if (D > MAXD) D = MAXD;

    __shared__ float rsh[MAXD][N_DIM];
    __shared__ float rn2sh[MAXD];
    __shared__ int   bsh[MAXD];

    for (int d = 0; d < D; ++d) {
        const int b = list[t * MAXD + d];          // uniform across block
        if (threadIdx.x == 0) bsh[d] = b;
        rsh[d][threadIdx.x] = reprs[(size_t)b * N_DIM + threadIdx.x];
    }
    __syncthreads();

    // per-detection squared norms (once per track, not per slot)
    for (int d = wave; d < D; d += 4) {
        const float4 r = reinterpret_cast<const float4*>(&rsh[d][0])[lane];
        float ss = r.x * r.x + r.y * r.y + r.z * r.z + r.w * r.w;
        #pragma unroll
        for (int o = 32; o >= 1; o >>= 1) ss += __shfl_xor(ss, o, 64);
        if (lane == 0) rn2sh[d] = ss;
    }
    __syncthreads();

    // preload this wave's 16 memory rows -> 256 B/lane outstanding
    float4 m[16];
    #pragma unroll
    for (int s = 0; s < 16; ++s)
        m[s] = reinterpret_cast<const float4*>(memory + wbase + (size_t)s * N_DIM)[lane];

    #pragma unroll
    for (int s = 0; s < 16; ++s) {
        const int q = wave * 16 + s;

        unsigned long long best = ~0ULL;
        float bestDot = 0.0f;
        int   bestD   = 0;
        for (int d = 0; d < D; ++d) {
            const float4 r = reinterpret_cast<const float4*>(&rsh[d][0])[lane];
            float dot = m[s].x * r.x + m[s].y * r.y + m[s].z * r.z + m[s].w * r.w;
            #pragma unroll
            for (int o = 32; o >= 1; o >>= 1) dot += __shfl_xor(dot, o, 64);
            const unsigned long long p =
                ((unsigned long long)f32_key(dot) << 32) |
                ((uint32_t)bsh[d] << 6) | (uint32_t)d;
            if (p < best) { best = p; bestDot = dot; bestD = d; }
        }

        const float a  = alpha[q];
        const float na = 1.0f - a;
        const float4 r = reinterpret_cast<const float4*>(&rsh[bestD][0])[lane];

        float4 u;
        u.x = a * m[s].x + na * r.x;
        u.y = a * m[s].y + na * r.y;
        u.z = a * m[s].z + na * r.z;
        u.w = a * m[s].w + na * r.w;

        const float nrm2 = a * a + na * na * rn2sh[bestD] + 2.0f * a * na * bestDot;
        const float sc = 1.0f / (sqrtf(nrm2) + EPSF);
        u.x *= sc; u.y *= sc; u.z *= sc; u.w *= sc;
        reinterpret_cast<float4*>(out + wbase + (size_t)s * N_DIM)[lane] = u;
    }
}

extern "C" void kernel_launch(void* const* d_in, const int* in_sizes, int n_in,
                              void* d_out, int out_size, void* d_ws, size_t ws_size,
                              hipStream_t stream) {
    const float* reprs      = (const float*)d_in[0];
    const float* memory     = (const float*)d_in[1];
    const float* alpha      = (const float*)d_in[2];
    const int*   track_idxs = (const int*)d_in[3];   // harness converts int64 -> int32
    float*       out        = (float*)d_out;

    int* cnt  = (int*)d_ws;                                // 16 KB
    int* list = (int*)((char*)d_ws + T_TRK * sizeof(int)); // 512 KB

    hipMemsetAsync(cnt, 0, T_TRK * sizeof(int), stream);
    build_lists<<<B_DET / 256, 256, 0, stream>>>(track_idxs, cnt, list);
    fused_update<<<T_TRK, 256, 0, stream>>>(reprs, memory, alpha, cnt, list, out);
}

// Round 5
// 122.667 us; speedup vs baseline: 1.5135x; 1.1908x over previous
//
#include <hip/hip_runtime.h>
#include <stdint.h>

#define B_DET 8192
#define N_DIM 256
#define T_TRK 4096
#define Q_SLOT 64
#define MAXD   64          // list capacity (Binomial(8192,1/4096): P(D>64) ~ 0)
#define CHUNK  16          // detections staged in LDS per chunk
#define EPSF   1e-9f

// Monotone map fp32 -> uint32 (ascending). No NaNs expected in this data.
__device__ __forceinline__ uint32_t f32_key(float f) {
    uint32_t u = __float_as_uint(f);
    return (u & 0x80000000u) ? ~u : (u | 0x80000000u);
}

// Pass 1: bucket detections by track. cnt[] must be zeroed beforehand.
// List order is nondeterministic (atomics) but the argmin below compares by
// (key, b, d) VALUES, so the selected detection is order-independent.
__global__ __launch_bounds__(256)
void build_lists(const int* __restrict__ track_idxs,
                 int* __restrict__ cnt, int* __restrict__ list) {
    const int b = blockIdx.x * 256 + threadIdx.x;
    const int t = track_idxs[b];
    const int slot = atomicAdd(&cnt[t], 1);
    if (slot < MAXD) list[t * MAXD + slot] = b;
}

// Pass 2: one block per track, 4 waves. Each wave owns 16 slots, processed as
// 2 passes of 8 (VGPR control). Per detection: per-lane partial dots for all
// 8 slots, then BATCHED 6-stage butterfly (8 independent shfls per stage ->
// latency hidden). Argmin via packed (f32key(dot), b, d) u64 min == exact
// first-occurrence tie-break. Final norm: batched butterfly of ||u||^2.
__global__ __launch_bounds__(256)
void fused_update(const float* __restrict__ reprs,
                  const float* __restrict__ memory,
                  const float* __restrict__ alpha,
                  const int* __restrict__ cnt,
                  const int* __restrict__ list,
                  float* __restrict__ out) {
    const int t    = blockIdx.x;
    const int wave = threadIdx.x >> 6;
    const int lane = threadIdx.x & 63;
    const size_t wbase = ((size_t)t * Q_SLOT + wave * 16) * N_DIM;

    int D = cnt[t];
    if (D == 0) {
        // untouched track: batched 16-row register copy (16 loads in flight)
        float4 m[16];
        #pragma unroll
        for (int s = 0; s < 16; ++s)
            m[s] = reinterpret_cast<const float4*>(memory + wbase + (size_t)s * N_DIM)[lane];
        #pragma unroll
        for (int s = 0; s < 16; ++s)
            reinterpret_cast<float4*>(out + wbase + (size_t)s * N_DIM)[lane] = m[s];
        return;
    }
    if (D > MAXD) D = MAXD;
    const int nchunks = (D + CHUNK - 1) / CHUNK;

    __shared__ float rsh[CHUNK][N_DIM];
    __shared__ int   bdsh[CHUNK];      // packed (b << 6) | d_global

    #pragma unroll
    for (int pass = 0; pass < 2; ++pass) {
        const int sbase = pass * 8;    // this pass covers slots wave*16+sbase+0..7

        float4 m[8];
        #pragma unroll
        for (int s = 0; s < 8; ++s)
            m[s] = reinterpret_cast<const float4*>(
                memory + wbase + (size_t)(sbase + s) * N_DIM)[lane];

        unsigned long long best[8];
        #pragma unroll
        for (int s = 0; s < 8; ++s) best[s] = ~0ULL;

        for (int c = 0; c < nchunks; ++c) {
            __syncthreads();           // previous chunk fully consumed
            const int dlim = min(CHUNK, D - c * CHUNK);
            for (int dd = 0; dd < dlim; ++dd) {
                const int dg = c * CHUNK + dd;
                const int b  = list[t * MAXD + dg];      // uniform across block
                if (threadIdx.x == 0) bdsh[dd] = (b << 6) | dg;
                rsh[dd][threadIdx.x] = reprs[(size_t)b * N_DIM + threadIdx.x];
            }
            __syncthreads();

            for (int dd = 0; dd < dlim; ++dd) {
                const float4 r = reinterpret_cast<const float4*>(&rsh[dd][0])[lane];
                float part[8];
                #pragma unroll
                for (int s = 0; s < 8; ++s)
                    part[s] = m[s].x * r.x + m[s].y * r.y + m[s].z * r.z + m[s].w * r.w;
                #pragma unroll
                for (int o = 32; o >= 1; o >>= 1) {
                    #pragma unroll
                    for (int s = 0; s < 8; ++s)
                        part[s] += __shfl_xor(part[s], o, 64);
                }
                const uint32_t bd = (uint32_t)bdsh[dd];
                #pragma unroll
                for (int s = 0; s < 8; ++s) {
                    const unsigned long long p =
                        ((unsigned long long)f32_key(part[s]) << 32) | bd;
                    best[s] = (p < best[s]) ? p : best[s];
                }
            }
        }

        // epilogue: blend with chosen r (re-fetched from global; L2-hot, and
        // correct even when the winner came from an earlier, overwritten chunk)
        float4 u[8];
        float  ss[8];
        #pragma unroll
        for (int s = 0; s < 8; ++s) {
            const int bsel = (int)(((uint32_t)best[s]) >> 6);
            const float a  = alpha[wave * 16 + sbase + s];
            const float na = 1.0f - a;
            const float4 r = reinterpret_cast<const float4*>(
                reprs + (size_t)bsel * N_DIM)[lane];
            u[s].x = a * m[s].x + na * r.x;
            u[s].y = a * m[s].y + na * r.y;
            u[s].z = a * m[s].z + na * r.z;
            u[s].w = a * m[s].w + na * r.w;
            ss[s] = u[s].x * u[s].x + u[s].y * u[s].y
                  + u[s].z * u[s].z + u[s].w * u[s].w;
        }
        #pragma unroll
        for (int o = 32; o >= 1; o >>= 1) {
            #pragma unroll
            for (int s = 0; s < 8; ++s)
                ss[s] += __shfl_xor(ss[s], o, 64);
        }
        #pragma unroll
        for (int s = 0; s < 8; ++s) {
            const float sc = 1.0f / (sqrtf(ss[s]) + EPSF);
            float4 w;
            w.x = u[s].x * sc; w.y = u[s].y * sc;
            w.z = u[s].z * sc; w.w = u[s].w * sc;
            reinterpret_cast<float4*>(
                out + wbase + (size_t)(sbase + s) * N_DIM)[lane] = w;
        }
    }
}

extern "C" void kernel_launch(void* const* d_in, const int* in_sizes, int n_in,
                              void* d_out, int out_size, void* d_ws, size_t ws_size,
                              hipStream_t stream) {
    const float* reprs      = (const float*)d_in[0];
    const float* memory     = (const float*)d_in[1];
    const float* alpha      = (const float*)d_in[2];
    const int*   track_idxs = (const int*)d_in[3];   // harness converts int64 -> int32
    float*       out        = (float*)d_out;

    int* cnt  = (int*)d_ws;                                // 16 KB
    int* list = (int*)((char*)d_ws + T_TRK * sizeof(int)); // 1 MB (MAXD=64)

    hipMemsetAsync(cnt, 0, T_TRK * sizeof(int), stream);
    build_lists<<<B_DET / 256, 256, 0, stream>>>(track_idxs, cnt, list);
    fused_update<<<T_TRK, 256, 0, stream>>>(reprs, memory, alpha, cnt, list, out);
}